// Round 6
// baseline (626.879 us; speedup 1.0000x reference)
//
#include <hip/hip_runtime.h>

typedef unsigned short u16;
typedef unsigned int u32;
typedef __attribute__((ext_vector_type(8))) short short8;   // 8 bf16 MFMA frag (4 VGPRs)
typedef __attribute__((ext_vector_type(4))) float f32x4;
typedef __attribute__((ext_vector_type(2))) unsigned int u32x2;
typedef __attribute__((ext_vector_type(4))) unsigned int u32x4;

#define BB 4
#define CC 256
#define NT 4096
#define L2E 1.4426950408889634f

__device__ __forceinline__ float b2f(u16 v) {
    union { u32 u; float f; } c; c.u = ((u32)v) << 16; return c.f;
}
__device__ __forceinline__ u16 f2b(float f) {
    union { float f; u32 u; } c; c.f = f;
    u32 u = c.u;
    return (u16)((u + 0x7fffu + ((u >> 16) & 1u)) >> 16);   // RNE
}

// ---------------------------------------------------------------------------
// K1: fused projections (fp32 in). Y = [Wq;Wk;Wv](320x256) @ x(256x4096) per b.
// fp32 VALU GEMM, LDS tiles, 4x4 reg tiling. (unchanged — R1 version)
// ---------------------------------------------------------------------------
__global__ __launch_bounds__(256) void kproj(
    const float* __restrict__ x,
    const float* __restrict__ Wq, const float* __restrict__ bq,
    const float* __restrict__ Wk, const float* __restrict__ bk,
    const float* __restrict__ Wv, const float* __restrict__ bv,
    u16* __restrict__ qh, u16* __restrict__ ql,
    u16* __restrict__ kh, u16* __restrict__ kl,
    u16* __restrict__ pvw)
{
    __shared__ __align__(16) float lA[32][68];   // [k][row]
    __shared__ __align__(16) float lX[32][68];   // [k][col]
    const int mt = blockIdx.x, nt = blockIdx.y, b = blockIdx.z;
    const int t = threadIdx.x;
    const int tx = t & 15, ty = t >> 4;
    const int n0 = nt * 64;

    float acc[4][4];
    #pragma unroll
    for (int i = 0; i < 4; ++i)
        #pragma unroll
        for (int j = 0; j < 4; ++j) acc[i][j] = 0.f;

    const int rA = t >> 2, kqA = (t & 3) * 8;
    const int rgA = mt * 64 + rA;
    const float* wrow;
    if (rgA < 32)      wrow = Wq + rgA * 256;
    else if (rgA < 64) wrow = Wk + (rgA - 32) * 256;
    else               wrow = Wv + (rgA - 64) * 256;
    const int kX = t >> 3, nn8 = (t & 7) * 8;
    const float* xrow = x + ((size_t)(b * CC + kX)) * NT + n0 + nn8;

    for (int k0 = 0; k0 < 256; k0 += 32) {
        f32x4 wa = *(const f32x4*)(wrow + k0 + kqA);
        f32x4 wb = *(const f32x4*)(wrow + k0 + kqA + 4);
        f32x4 xa = *(const f32x4*)(xrow + (size_t)k0 * NT);
        f32x4 xb = *(const f32x4*)(xrow + (size_t)k0 * NT + 4);
        __syncthreads();
        #pragma unroll
        for (int j = 0; j < 4; ++j) {
            lA[kqA + j    ][rA] = wa[j];
            lA[kqA + j + 4][rA] = wb[j];
        }
        *(f32x4*)&lX[kX][nn8]     = xa;
        *(f32x4*)&lX[kX][nn8 + 4] = xb;
        __syncthreads();
        #pragma unroll
        for (int k = 0; k < 32; ++k) {
            f32x4 av  = *(const f32x4*)&lA[k][ty * 4];
            f32x4 xvv = *(const f32x4*)&lX[k][tx * 4];
            #pragma unroll
            for (int i = 0; i < 4; ++i)
                #pragma unroll
                for (int j = 0; j < 4; ++j)
                    acc[i][j] = fmaf(av[i], xvv[j], acc[i][j]);
        }
    }

    #pragma unroll
    for (int i = 0; i < 4; ++i) {
        const int rg = mt * 64 + ty * 4 + i;
        float bias;
        if (rg < 32)      bias = bq[rg];
        else if (rg < 64) bias = bk[rg - 32];
        else              bias = bv[rg - 64];
        #pragma unroll
        for (int j = 0; j < 4; ++j) {
            const int n = n0 + tx * 4 + j;
            const float val = acc[i][j] + bias;
            const u16 h = f2b(val);
            const u16 l = f2b(val - b2f(h));
            if (rg < 32) {
                const size_t idx = ((size_t)(b * NT + n)) * 32 + rg;
                qh[idx] = h; ql[idx] = l;
            } else if (rg < 64) {
                const size_t idx = ((size_t)(b * NT + n)) * 32 + (rg - 32);
                kh[idx] = h; kl[idx] = l;
            } else {
                pvw[((size_t)b * CC + (rg - 64)) * NT + n] = f2b(val);
            }
        }
    }
}

// ---------------------------------------------------------------------------
// K2 (fused) v3: sa + out. Swapped QK^T. BM=16, 4 waves/block, grid 1024:
//  - 4 blocks/CU (16 waves/CU): barrier couples only 4 waves; independent
//    blocks on one CU overlap each other's stalls (R5's 8-wave 2-block
//    lockstep was the serializer: all waves hit the LDS pipe simultaneously)
//  - LDS p-tile [3][16][144 u16] (288B row stride, 16B-aligned, ≡8 mod 128B):
//    row enters the bank index via the stride -> uniform ≤4-way on b128 reads
//    (R5's XOR swizzle was broken for this geometry: row*256B ≡ 0 mod 128B,
//    quad^row-XOR collided -> measured 8-way, 5.24M conflict cycles)
//  - per-wave PV = 4 c-chunks (c = cq*64..+63): each wave reads the tile once
//    per k-slice (4KB/period, half of R5's 8KB)
//  - pa A-frags: two static groups (pA/pB), reloaded right after consumption,
//    reused 2 k-slots later (static names per rule #20)
//  - triple-buffer + 1 barrier/period (race-free: write target of p+1 is
//    (p+2)%3, disjoint from read buf p%3), counted lgkmcnt only, setprio on PV
// ---------------------------------------------------------------------------
#define MFMA_BF16(A, B, C) __builtin_amdgcn_mfma_f32_16x16x32_bf16(A, B, C, 0, 0, 0)
#define RS   288            // LDS row stride, bytes
#define LBUF 4608           // one buffer = 16 rows * 288B

__global__ __launch_bounds__(256, 4) void ksaout(
    const u16* __restrict__ qh, const u16* __restrict__ ql,
    const u16* __restrict__ kh, const u16* __restrict__ kl,
    const float* __restrict__ valid, const u16* __restrict__ pvw,
    const float* __restrict__ x, const float* __restrict__ gamma,
    float* __restrict__ sa, float* __restrict__ outp)
{
    __shared__ __align__(16) u16 lP[3 * 16 * 144];   // 13.8 KB
    __shared__ float sred[4][16];
    const int b    = blockIdx.y;
    const int m0   = blockIdx.x * 16;
    const int t    = threadIdx.x;
    const int lane = t & 63;
    const int cq   = t >> 6;          // wave id = ct-phase 0..3
    const int quad = lane >> 4, l16 = lane & 15;

    // Q fragments (B-operand of swapped QK^T), rows m0+l16
    const size_t qbase = ((size_t)(b * NT + m0 + l16)) * 32 + quad * 8;
    const short8 aqh = *(const short8*)(qh + qbase);
    const short8 aql = *(const short8*)(ql + qbase);
    // K fragment base (A-operand): key row ct*16+l16, channel chunk quad*8
    const size_t kbase = (size_t)b * NT * 32 + (size_t)l16 * 32 + quad * 8;
    const float* vbase = valid + (size_t)b * NT;
    const f32x4 zero = {0.f, 0.f, 0.f, 0.f};

    // ---------------- phase 1: row sums ----------------
    float sacc = 0.f;
    {
        short8 nbh = *(const short8*)(kh + kbase + (size_t)cq * 512);
        short8 nbl = *(const short8*)(kl + kbase + (size_t)cq * 512);
        f32x4  nv4 = *(const f32x4*)(vbase + cq * 16 + quad * 4);
        for (int s = 0; s < 64; ++s) {
            short8 bh = nbh, bl = nbl;
            f32x4 v4 = nv4;
            if (s + 1 < 64) {
                const int ct = (s + 1) * 4 + cq;
                nbh = *(const short8*)(kh + kbase + (size_t)ct * 512);
                nbl = *(const short8*)(kl + kbase + (size_t)ct * 512);
                nv4 = *(const f32x4*)(vbase + ct * 16 + quad * 4);
            }
            f32x4 d = MFMA_BF16(bh, aqh, zero);
            d = MFMA_BF16(bh, aql, d);
            d = MFMA_BF16(bl, aqh, d);
            #pragma unroll
            for (int i = 0; i < 4; ++i)
                sacc += v4[i] * exp2f(fminf(d[i], 60.f) * L2E);
        }
    }
    sacc += __shfl_xor(sacc, 16, 64);
    sacc += __shfl_xor(sacc, 32, 64);
    if (lane < 16) sred[cq][l16] = sacc;
    __syncthreads();
    const float inv = 1.0f / (sred[0][l16] + sred[1][l16] +
                              sred[2][l16] + sred[3][l16]);

    // ---------------- phase 2: emit sa + PV accumulate ----------------
    float* sap = sa + ((size_t)(b * NT + m0 + l16)) * NT;
    char* lpB = (char*)&lP[0];
    const int lwoff = l16 * RS + cq * 32 + quad * 8;
    // pv A-frags: wave cq owns out rows c = cq*64 + j*16 + l16, j=0..3
    const u16* pva0 = pvw + ((size_t)(b * CC + cq * 64 + l16)) * NT + quad * 8;
    const u16* pva1 = pva0 + (size_t)16 * NT;
    const u16* pva2 = pva0 + (size_t)32 * NT;
    const u16* pva3 = pva0 + (size_t)48 * NT;

    f32x4 acc0 = {0,0,0,0}, acc1 = {0,0,0,0}, acc2 = {0,0,0,0}, acc3 = {0,0,0,0};

#define LOADQK(S, BH, BL, VV)                                                  \
    { const int ct_ = (S) * 4 + cq;                                            \
      BH = *(const short8*)(kh + kbase + (size_t)ct_ * 512);                   \
      BL = *(const short8*)(kl + kbase + (size_t)ct_ * 512);                   \
      VV = *(const f32x4*)(vbase + ct_ * 16 + quad * 4); }

#define ASTEP(S, BUF, BH, BL, VV)                                              \
    { f32x4 d = MFMA_BF16(BH, aqh, zero);                                      \
      d = MFMA_BF16(BH, aql, d);                                               \
      d = MFMA_BF16(BL, aqh, d);                                               \
      f32x4 val;                                                               \
      _Pragma("unroll")                                                        \
      for (int i = 0; i < 4; ++i)                                              \
          val[i] = VV[i] * exp2f(fminf(d[i], 60.f) * L2E) * inv;               \
      *(f32x4*)(sap + (size_t)(S) * 64 + cq * 16 + quad * 4) = val;            \
      u32x2 pk;                                                                \
      pk[0] = (u32)f2b(val[0]) | ((u32)f2b(val[1]) << 16);                     \
      pk[1] = (u32)f2b(val[2]) | ((u32)f2b(val[3]) << 16);                     \
      *(u32x2*)(lpB + (BUF) * LBUF + lwoff + ((S) & 1) * 128) = pk; }

#define LOADPA(G0, G1, G2, G3, OFF)                                            \
    { G0 = *(const short8*)(pva0 + (OFF));                                     \
      G1 = *(const short8*)(pva1 + (OFF));                                     \
      G2 = *(const short8*)(pva2 + (OFF));                                     \
      G3 = *(const short8*)(pva3 + (OFF)); }

#define PVSLOT(BT, G0, G1, G2, G3)                                             \
    { acc0 = MFMA_BF16(G0, BT, acc0);                                          \
      acc1 = MFMA_BF16(G1, BT, acc1);                                          \
      acc2 = MFMA_BF16(G2, BT, acc2);                                          \
      acc3 = MFMA_BF16(G3, BT, acc3); }

    short8 kbh0, kbl0, kbh1, kbl1;
    f32x4 kv0, kv1;
    short8 pA0, pA1, pA2, pA3, pB0, pB1, pB2, pB3;

    // prologue: steps 0,1 -> buf0; QK for steps 2,3; pa slots k0,k1 of period 0
    LOADQK(0, kbh0, kbl0, kv0);
    LOADQK(1, kbh1, kbl1, kv1);
    ASTEP(0, 0, kbh0, kbl0, kv0);
    ASTEP(1, 0, kbh1, kbl1, kv1);
    LOADQK(2, kbh0, kbl0, kv0);
    LOADQK(3, kbh1, kbl1, kv1);
    LOADPA(pA0, pA1, pA2, pA3, 0);
    LOADPA(pB0, pB1, pB2, pB3, 32);
    asm volatile("s_waitcnt lgkmcnt(0)" ::: "memory");
    __builtin_amdgcn_sched_barrier(0);
    __builtin_amdgcn_s_barrier();
    __builtin_amdgcn_sched_barrier(0);

    for (int p = 0; p < 32; ++p) {
        const int rbuf = p % 3;
        if (p < 31) {
            const int wbuf = (p + 1) % 3;
            ASTEP(2 * p + 2, wbuf, kbh0, kbl0, kv0);
            ASTEP(2 * p + 3, wbuf, kbh1, kbl1, kv1);
            if (p < 30) {
                LOADQK(2 * p + 4, kbh0, kbl0, kv0);
                LOADQK(2 * p + 5, kbh1, kbl1, kv1);
            }
            asm volatile("s_waitcnt lgkmcnt(0)" ::: "memory");
            __builtin_amdgcn_sched_barrier(0);
            __builtin_amdgcn_s_barrier();
            __builtin_amdgcn_sched_barrier(0);
        }
        const char* lb = lpB + rbuf * LBUF + l16 * RS + quad * 16;
        // issue all 4 tile frags up front, then 4 slots of 4 MFMAs + pa reload
        short8 bt0 = *(const short8*)(lb);
        short8 bt1 = *(const short8*)(lb + 64);
        short8 bt2 = *(const short8*)(lb + 128);
        short8 bt3 = *(const short8*)(lb + 192);
        const size_t koff = (size_t)p * 128;
        __builtin_amdgcn_s_setprio(1);
        PVSLOT(bt0, pA0, pA1, pA2, pA3);                 // k0: consume A
        LOADPA(pA0, pA1, pA2, pA3, koff + 64);           //     reload A <- k2
        PVSLOT(bt1, pB0, pB1, pB2, pB3);                 // k1: consume B
        LOADPA(pB0, pB1, pB2, pB3, koff + 96);           //     reload B <- k3
        PVSLOT(bt2, pA0, pA1, pA2, pA3);                 // k2: consume A
        if (p < 31) LOADPA(pA0, pA1, pA2, pA3, koff + 128);      // A <- p+1,k0
        PVSLOT(bt3, pB0, pB1, pB2, pB3);                 // k3: consume B
        if (p < 31) LOADPA(pB0, pB1, pB2, pB3, koff + 160);      // B <- p+1,k1
        __builtin_amdgcn_s_setprio(0);
    }
#undef LOADQK
#undef ASTEP
#undef LOADPA
#undef PVSLOT

    // epilogue: out[c = cq*64 + j*16 + quad*4 + i][m = m0 + l16]
    const float g = gamma[0];
    const int m = m0 + l16;
    #pragma unroll
    for (int j = 0; j < 4; ++j) {
        f32x4 acc = (j == 0) ? acc0 : (j == 1) ? acc1 : (j == 2) ? acc2 : acc3;
        #pragma unroll
        for (int i = 0; i < 4; ++i) {
            const int c = cq * 64 + j * 16 + quad * 4 + i;
            const size_t idx = ((size_t)(b * CC + c)) * NT + m;
            outp[idx] = g * acc[i] + x[idx];
        }
    }
}

extern "C" void kernel_launch(void* const* d_in, const int* in_sizes, int n_in,
                              void* d_out, int out_size, void* d_ws, size_t ws_size,
                              hipStream_t stream)
{
    const float* x     = (const float*)d_in[0];
    const float* valid = (const float*)d_in[1];
    const float* Wq    = (const float*)d_in[2];
    const float* bq    = (const float*)d_in[3];
    const float* Wk    = (const float*)d_in[4];
    const float* bk    = (const float*)d_in[5];
    const float* Wv    = (const float*)d_in[6];
    const float* bv    = (const float*)d_in[7];
    const float* gamma = (const float*)d_in[8];

    float* outp = (float*)d_out;
    float* sa   = outp + (size_t)BB * CC * NT;      // output chunk 1 [B][N][N] fp32

    u16* qh  = (u16*)d_ws;                          // [B][N][32] bf16, 1 MB each
    u16* ql  = qh + (size_t)BB * NT * 32;
    u16* kh  = ql + (size_t)BB * NT * 32;
    u16* kl  = kh + (size_t)BB * NT * 32;
    u16* pvw = kl + (size_t)BB * NT * 32;           // [B][C][N] bf16, 8 MB

    kproj<<<dim3(5, 64, BB), 256, 0, stream>>>(x, Wq, bq, Wk, bk, Wv, bv,
                                               qh, ql, kh, kl, pvw);
    ksaout<<<dim3(256, BB), 256, 0, stream>>>(qh, ql, kh, kl, valid, pvw,
                                              x, gamma, sa, outp);
}